// Round 8
// baseline (414.529 us; speedup 1.0000x reference)
//
#include <hip/hip_runtime.h>
#include <math.h>

#define BATCH 128
#define TLEN 512
#define XF 266
#define HID 192
#define NC 250

typedef __attribute__((ext_vector_type(8))) short short8;
typedef __attribute__((ext_vector_type(4))) float float4v;

#define NL2E  -1.4426950408889634f
#define NL2E2 -2.8853900817779268f

// fp32 -> bf16 (RNE)
__device__ __forceinline__ unsigned short f2bf(float f) {
  unsigned u = __float_as_uint(f);
  u += 0x7FFF + ((u >> 16) & 1);
  return (unsigned short)(u >> 16);
}
__device__ __forceinline__ float bf2f(unsigned short s) {
  return __uint_as_float(((unsigned)s) << 16);
}

// single-instruction exp2 (v_exp_f32)
__device__ __forceinline__ float exp2i(float x) {
#if __has_builtin(__builtin_amdgcn_exp2f)
  return __builtin_amdgcn_exp2f(x);
#else
  float r;
  asm("v_exp_f32 %0, %1" : "=v"(r) : "v"(x));
  return r;
#endif
}

// LDS-only barrier: does NOT drain vmcnt.
__device__ __forceinline__ void lds_barrier() {
  asm volatile("s_waitcnt lgkmcnt(0)\n\ts_barrier" ::: "memory");
}

// ---------------- K1: feature prep (VECTOR STORES) ------------------------
// hoist: hands [tile8][t][row16][64], tile=b>>4, row=b&15 (plain rows)
//        arms  [tile8][t][m32][8],  tile=b>>4, va=b&15,
//                row (va>>3)*16 + ((va&7)>>1)*4 + (va&1)
// fb: hands [tile8][t][m16][48] row=b&15; arms [tile4][t][m32][8] row=b&31

template <int HS>
__device__ __forceinline__ void norm_hand_s(const float* __restrict__ xp,
                                            unsigned short* __restrict__ fp,
                                            int p0, int refp) {
  float rx = xp[2 * refp], ry = xp[2 * refp + 1];
  float px[21], py[21];
  float minx = 1e30f, maxx = -1e30f, miny = 1e30f, maxy = -1e30f;
#pragma unroll
  for (int i = 0; i < 21; ++i) {
    float ax = xp[2 * (p0 + i)] - rx;
    float ay = xp[2 * (p0 + i) + 1] - ry;
    px[i] = ax; py[i] = ay;
    minx = fminf(minx, ax); maxx = fmaxf(maxx, ax);
    miny = fminf(miny, ay); maxy = fmaxf(maxy, ay);
  }
  float s = fmaxf(maxx - minx, maxy - miny);
  if (s == 0.f) s = 1.f;
  float inv = 1.f / s;
#pragma unroll
  for (int j = 0; j < HS / 8; ++j) {
    short8 v;
#pragma unroll
    for (int k = 0; k < 8; ++k) {
      int i = 8 * j + k;  // compile-time constant after unroll
      float val = (i < 42) ? ((i & 1) ? py[i >> 1] : px[i >> 1]) * inv : 0.f;
      v[k] = (short)f2bf(val);
    }
    *(short8*)(fp + 8 * j) = v;
  }
}

__device__ __forceinline__ void norm_arm_s(const float* __restrict__ xp,
                                           unsigned short* __restrict__ fp,
                                           int a, int b, int c) {
  float rx = xp[0], ry = xp[1];
  float x0 = xp[2 * a] - rx, y0 = xp[2 * a + 1] - ry;
  float x1 = xp[2 * b] - rx, y1 = xp[2 * b + 1] - ry;
  float x2 = xp[2 * c] - rx, y2 = xp[2 * c + 1] - ry;
  float w = fmaxf(fmaxf(x0, x1), x2) - fminf(fminf(x0, x1), x2);
  float h = fmaxf(fmaxf(y0, y1), y2) - fminf(fminf(y0, y1), y2);
  float s = fmaxf(w, h);
  if (s == 0.f) s = 1.f;
  float inv = 1.f / s;
  short8 v;
  v[0] = (short)f2bf(x0 * inv); v[1] = (short)f2bf(y0 * inv);
  v[2] = (short)f2bf(x1 * inv); v[3] = (short)f2bf(y1 * inv);
  v[4] = (short)f2bf(x2 * inv); v[5] = (short)f2bf(y2 * inv);
  v[6] = 0; v[7] = 0;
  *(short8*)fp = v;
}

__global__ __launch_bounds__(256) void prep_kernel(
    const float* __restrict__ x,
    unsigned short* __restrict__ fHR, unsigned short* __restrict__ fHL,
    unsigned short* __restrict__ fAR, unsigned short* __restrict__ fAL,
    int mode) {
  int idx = blockIdx.x * 256 + threadIdx.x;
  if (idx >= BATCH * TLEN) return;
  int b = idx >> 9, t = idx & 511;
  const float* xp = x + (size_t)idx * XF;
  if (mode) {
    size_t hoff = (((size_t)(b >> 4) * TLEN + t) * 16 + (b & 15)) * 64;
    int va = b & 15;
    int rowa = (va >> 3) * 16 + ((va & 7) >> 1) * 4 + (va & 1);
    size_t aoff = (((size_t)(b >> 4) * TLEN + t) * 32 + rowa) * 8;
    norm_hand_s<64>(xp, fHR + hoff, 112, 10);  // right hand, ref pt 10
    norm_hand_s<64>(xp, fHL + hoff, 91, 9);    // left hand, ref pt 9
    norm_arm_s(xp, fAR + aoff, 6, 8, 10);      // right arm
    norm_arm_s(xp, fAL + aoff, 5, 7, 9);       // left arm
  } else {
    size_t hoff = (((size_t)(b >> 4) * TLEN + t) * 16 + (b & 15)) * 48;
    size_t aoff = (((size_t)(b >> 5) * TLEN + t) * 32 + (b & 31)) * 8;
    norm_hand_s<48>(xp, fHR + hoff, 112, 10);
    norm_hand_s<48>(xp, fHL + hoff, 91, 9);
    norm_arm_s(xp, fAR + aoff, 6, 8, 10);
    norm_arm_s(xp, fAL + aoff, 5, 7, 9);
  }
}

// ---------------- K1b: weight packing (FB MODE ONLY) ----------------------

__global__ __launch_bounds__(256) void pack_kernel(
    const float* __restrict__ wi_rh, const float* __restrict__ wh_rh,
    const float* __restrict__ wi_ra, const float* __restrict__ wh_ra,
    const float* __restrict__ wi_lh, const float* __restrict__ wh_lh,
    const float* __restrict__ wi_la, const float* __restrict__ wh_la,
    unsigned short* __restrict__ btA_r, unsigned short* __restrict__ btA_l,
    unsigned short* __restrict__ btArm_r, unsigned short* __restrict__ btArm_l) {
  int blk = blockIdx.x, tid = threadIdx.x;
  if (blk < 2) {
    const float* wi = blk ? wi_lh : wi_rh;
    const float* wh = blk ? wh_lh : wh_rh;
    unsigned short* dst = blk ? btA_l : btA_r;
    for (int i = tid; i < 256 * 128; i += 256) {
      int g = i >> 7, k = i & 127;
      float s = ((g >> 6) == 2) ? NL2E2 : NL2E;
      float v = (k < 42) ? wi[g * 42 + k] : (k < 64 ? 0.f : wh[g * 64 + (k - 64)]);
      dst[i] = f2bf(v * s);
    }
  } else {
    const float* wi = (blk == 3) ? wi_la : wi_ra;
    const float* wh = (blk == 3) ? wh_la : wh_ra;
    unsigned short* dst = (blk == 3) ? btArm_l : btArm_r;
    for (int i = tid; i < 128 * 64; i += 256) {
      int g = i >> 6, k = i & 63;
      float s = ((g >> 5) == 2) ? NL2E2 : NL2E;
      float v = (k < 6) ? wi[g * 6 + k] : (k < 32 ? 0.f : wh[g * 32 + (k - 32)]);
      dst[i] = f2bf(v * s);
    }
  }
}

// ---------------- K1c: input-projection pre-GEMM (hoist mode) ------------
// Both-side-coalesced pre layout. Instance = (tile, r): batches
// tile*16 + quad*4 + r. Per (inst,t) 1024 shorts:
//   off = jt*256 + quad*64 + n*4 + gate   (4 gates packed in one uint2)

__global__ __launch_bounds__(256, 1) void pregemm_kernel(
    const unsigned short* __restrict__ f64R, const unsigned short* __restrict__ f64L,
    const float* __restrict__ wiR, const float* __restrict__ wiL,
    const float* __restrict__ biR, const float* __restrict__ bhR,
    const float* __restrict__ biL, const float* __restrict__ bhL,
    unsigned short* __restrict__ preR, unsigned short* __restrict__ preL) {
  int bx = blockIdx.x;
  int lr = bx >> 7, tile = (bx >> 4) & 7, tc = bx & 15;
  const unsigned short* f64 = lr ? f64L : f64R;
  const float* wi = lr ? wiL : wiR;
  const float* bi = lr ? biL : biR;
  const float* bh = lr ? bhL : bhR;
  unsigned short* pre = lr ? preL : preR;
  int tid = threadIdx.x, lane = tid & 63;
  int jg = tid >> 6, n = lane & 15, quad = lane >> 4;

  short8 Vb[4][2];
  float bias[4];
#pragma unroll
  for (int q = 0; q < 4; ++q) {
    float sq = (q == 2) ? NL2E2 : NL2E;
    int g = q * 64 + jg * 16 + n;
    bias[q] = (bi[g] + bh[g]) * sq;
#pragma unroll
    for (int c = 0; c < 2; ++c) {
      short8 vb;
#pragma unroll
      for (int s = 0; s < 8; ++s) {
        int k = c * 32 + quad * 8 + s;
        vb[s] = (short)f2bf(k < 42 ? wi[g * 42 + k] * sq : 0.f);
      }
      Vb[q][c] = vb;
    }
  }

  const unsigned short* ap =
      f64 + ((size_t)(tile * 512 + tc * 32) * 16 + n) * 64 + quad * 8;
  short8 VaC0 = *(const short8*)ap;
  short8 VaC1 = *(const short8*)(ap + 32);
  ap += 1024;
  unsigned short* pb = pre + ((size_t)(tile * 4) * 512 + tc * 32) * 1024 +
                       jg * 256 + quad * 64 + n * 4;
  for (int i = 0; i < 32; ++i) {
    short8 VaN0, VaN1;
    if (i + 1 < 32) {
      VaN0 = *(const short8*)ap;
      VaN1 = *(const short8*)(ap + 32);
    }
    ap += 1024;
    float4v acc[4];
#pragma unroll
    for (int q = 0; q < 4; ++q) {
      acc[q] = (float4v){bias[q], bias[q], bias[q], bias[q]};
      acc[q] = __builtin_amdgcn_mfma_f32_16x16x32_bf16(VaC0, Vb[q][0], acc[q], 0, 0, 0);
      acc[q] = __builtin_amdgcn_mfma_f32_16x16x32_bf16(VaC1, Vb[q][1], acc[q], 0, 0, 0);
    }
#pragma unroll
    for (int r = 0; r < 4; ++r) {
      uint2 u;
      u.x = (unsigned)f2bf(acc[0][r]) | ((unsigned)f2bf(acc[1][r]) << 16);
      u.y = (unsigned)f2bf(acc[2][r]) | ((unsigned)f2bf(acc[3][r]) << 16);
      *(uint2*)(pb + (size_t)r * (512 * 1024)) = u;
    }
    pb += 1024;
    VaC0 = VaN0;
    VaC1 = VaN1;
  }
}

// ---------------- K2 (hoist): RV=1 MFMA LSTM recurrence -------------------
// Round-5 structure (4-wave instance, 1 barrier/step) + chain micro-opts:
//  - split accumulators accA/accB: the two CH MFMAs are now INDEPENDENT
//    (chain pays one MFMA latency, not two); act adds the RSEL components.
//  - persistent accumulators: non-RSEL components hold 0 (hands; zero A
//    rows) or unread junk (arms) forever -- only the RSEL component is
//    refreshed per step (accA[q][RSEL]=0, accB[q][RSEL]=pre/bias),
//    deleting ~12 v_mov of per-step zero-init.

template <int H, int CH, int STR, int MB, int SCH, int HOFF, bool HOIST, int RSEL, int BQS>
__device__ __forceinline__ void lstm_core1(
    unsigned short* __restrict__ Ab0, unsigned short* __restrict__ Ab1,
    const float* __restrict__ wq,   // hands: whh (4H x H); arms: whh
    const float* __restrict__ wx,   // arms: wih (4H x 6); hands unused
    const float* __restrict__ bi, const float* __restrict__ bh,  // arms only
    const unsigned short* __restrict__ featp,   // arms (tile base)
    const unsigned short* __restrict__ prep_,   // hands (instance base)
    unsigned short* __restrict__ combbase,      // combined + col offset
    int b0, int mrow0, int j0) {
  constexpr int XSH = MB * SCH * 8;
  int tid = threadIdx.x;
  int lane = tid & 63, n = lane & 15, quad = lane >> 4;

  // B fragments inline-converted from f32 (pre-scaled by -log2e / -2log2e)
  short8 Vb[4][2];
  float bias[4];
#pragma unroll
  for (int q = 0; q < 4; ++q) {
    float sq = (q == 2) ? NL2E2 : NL2E;
    int g = q * H + j0 + n;
    if (!HOIST) bias[q] = (bi[g] + bh[g]) * sq;
#pragma unroll
    for (int c = 0; c < 2; ++c) {
      short8 vb;
#pragma unroll
      for (int s = 0; s < 8; ++s) {
        int k = c * 32 + quad * 8 + s;
        float v;
        if (HOIST) {
          v = wq[(size_t)g * H + k];                       // K == H (h-only)
        } else {
          v = (k < 6) ? wx[g * 6 + k]
                      : (k >= 32 ? wq[g * 32 + (k - 32)] : 0.f);
        }
        vb[s] = (short)f2bf(v * sq);
      }
      Vb[q][c] = vb;
    }
  }

  for (int i = tid; i < MB * STR; i += 256) { Ab0[i] = 0; Ab1[i] = 0; }
  __syncthreads();  // zero-init visible before staging writes

  // x staging (arms): static even/odd regs
  bool st = false;
  unsigned short *xd0 = nullptr, *xd1 = nullptr;
  const unsigned short* fp = nullptr;
  short8 xE, xO;
  if (!HOIST) {
    st = tid < MB * SCH;
    xd0 = Ab0 + tid * STR;
    xd1 = Ab1 + tid * STR;
    fp = featp + tid * 8;
    if (st) {
      *(short8*)xd0 = *(const short8*)fp;            // feat[0] -> buf0
      xO = *(const short8*)(fp + XSH);               // feat[1]
      xE = *(const short8*)(fp + 2 * (size_t)XSH);   // feat[2]
    }
    fp += 3 * (size_t)XSH;
  }

  // packed-pre prefetch (hands): uint2 per step, static even/odd regs
  const unsigned short *ppE = nullptr, *ppO = nullptr;
  uint2 pE = {0, 0}, pO = {0, 0};
  if (HOIST) {
    const unsigned short* pp0 = prep_ + (size_t)(j0 >> 4) * 256 + quad * 64 + n * 4;
    pE = *(const uint2*)pp0;              // pre[0]
    pO = *(const uint2*)(pp0 + 1024);     // pre[1]
    ppE = pp0 + 2 * 1024;
    ppO = pp0 + 3 * 1024;
  }

  float cc = 0.f;
  // persistent split accumulators (see header comment)
  float4v accA[4], accB[4];
#pragma unroll
  for (int q = 0; q < 4; ++q) {
    accA[q] = (float4v){0.f, 0.f, 0.f, 0.f};
    accB[q] = (float4v){0.f, 0.f, 0.f, 0.f};
  }
  __syncthreads();

  const unsigned short* ard0 = Ab0 + (mrow0 + n) * STR;
  const unsigned short* ard1 = Ab1 + (mrow0 + n) * STR;
  unsigned short* hw0 = Ab0 + (mrow0 + quad * 4 + RSEL) * STR + HOFF + j0 + n;
  unsigned short* hw1 = Ab1 + (mrow0 + quad * 4 + RSEL) * STR + HOFF + j0 + n;
  unsigned short* cgp = combbase +
      ((size_t)(b0 + (mrow0 >> 1) + quad * BQS) * TLEN) * HID + j0 + n;

  for (int tt = 0; tt < TLEN; tt += 2) {
    // ------- even step t = tt (reads buf0, writes h to buf1) -------------
    {
      const int t = tt;
      short8 Va0 = *(const short8*)(ard0 + quad * 8);
      short8 Va1 = *(const short8*)(ard0 + 32 + quad * 8);

#pragma unroll
      for (int q = 0; q < 4; ++q) accA[q][RSEL] = 0.f;
      if (HOIST) {
        accB[0][RSEL] = __uint_as_float(pE.x << 16);
        accB[1][RSEL] = __uint_as_float(pE.x & 0xffff0000u);
        accB[2][RSEL] = __uint_as_float(pE.y << 16);
        accB[3][RSEL] = __uint_as_float(pE.y & 0xffff0000u);
        if (t + 2 < TLEN) pE = *(const uint2*)ppE;   // refill (pre[t+2])
        ppE += 2 * 1024;
      } else {
#pragma unroll
        for (int q = 0; q < 4; ++q) accB[q][RSEL] = bias[q];
      }
#pragma unroll
      for (int q = 0; q < 4; ++q)
        accA[q] = __builtin_amdgcn_mfma_f32_16x16x32_bf16(Va0, Vb[q][0], accA[q], 0, 0, 0);
#pragma unroll
      for (int q = 0; q < 4; ++q)
        accB[q] = __builtin_amdgcn_mfma_f32_16x16x32_bf16(Va1, Vb[q][1], accB[q], 0, 0, 0);

      if (!HOIST) {
        if (st) {
          *(short8*)xd1 = xO;                          // feat[t+1] -> buf1
          if (t + 3 < TLEN) xO = *(const short8*)fp;   // feat[t+3]
        }
        fp += XSH;
      }

      float g0 = accA[0][RSEL] + accB[0][RSEL];
      float g1 = accA[1][RSEL] + accB[1][RSEL];
      float g2 = accA[2][RSEL] + accB[2][RSEL];
      float g3 = accA[3][RSEL] + accB[3][RSEL];
      float Ei = exp2i(g0);
      float Ef = exp2i(g1);
      float Eg = exp2i(g2);
      float Eo = exp2i(g3);
      float gf = __builtin_amdgcn_rcpf(1.f + Ef);
      float ig = (1.f - Eg) * __builtin_amdgcn_rcpf((1.f + Ei) * (1.f + Eg));
      float cv = fmaf(gf, cc, ig);
      cc = cv;
      float Ec = exp2i(cv * NL2E2);
      float hv = (1.f - Ec) * __builtin_amdgcn_rcpf((1.f + Eo) * (1.f + Ec));
      unsigned short hb = f2bf(hv);
      hw1[0] = hb;        // LDS for recurrence
      *cgp = hb;          // direct global store of combined
      cgp += HID;
      lds_barrier();
    }
    // ------- odd step t = tt+1 (reads buf1, writes h to buf0) ------------
    {
      const int t = tt + 1;
      short8 Va0 = *(const short8*)(ard1 + quad * 8);
      short8 Va1 = *(const short8*)(ard1 + 32 + quad * 8);

#pragma unroll
      for (int q = 0; q < 4; ++q) accA[q][RSEL] = 0.f;
      if (HOIST) {
        accB[0][RSEL] = __uint_as_float(pO.x << 16);
        accB[1][RSEL] = __uint_as_float(pO.x & 0xffff0000u);
        accB[2][RSEL] = __uint_as_float(pO.y << 16);
        accB[3][RSEL] = __uint_as_float(pO.y & 0xffff0000u);
        if (t + 2 < TLEN) pO = *(const uint2*)ppO;   // refill (pre[t+2])
        ppO += 2 * 1024;
      } else {
#pragma unroll
        for (int q = 0; q < 4; ++q) accB[q][RSEL] = bias[q];
      }
#pragma unroll
      for (int q = 0; q < 4; ++q)
        accA[q] = __builtin_amdgcn_mfma_f32_16x16x32_bf16(Va0, Vb[q][0], accA[q], 0, 0, 0);
#pragma unroll
      for (int q = 0; q < 4; ++q)
        accB[q] = __builtin_amdgcn_mfma_f32_16x16x32_bf16(Va1, Vb[q][1], accB[q], 0, 0, 0);

      if (!HOIST) {
        if (st) {
          if (t + 1 < TLEN) *(short8*)xd0 = xE;        // feat[t+1] -> buf0
          if (t + 3 < TLEN) xE = *(const short8*)fp;   // feat[t+3]
        }
        fp += XSH;
      }

      float g0 = accA[0][RSEL] + accB[0][RSEL];
      float g1 = accA[1][RSEL] + accB[1][RSEL];
      float g2 = accA[2][RSEL] + accB[2][RSEL];
      float g3 = accA[3][RSEL] + accB[3][RSEL];
      float Ei = exp2i(g0);
      float Ef = exp2i(g1);
      float Eg = exp2i(g2);
      float Eo = exp2i(g3);
      float gf = __builtin_amdgcn_rcpf(1.f + Ef);
      float ig = (1.f - Eg) * __builtin_amdgcn_rcpf((1.f + Ei) * (1.f + Eg));
      float cv = fmaf(gf, cc, ig);
      cc = cv;
      float Ec = exp2i(cv * NL2E2);
      float hv = (1.f - Ec) * __builtin_amdgcn_rcpf((1.f + Eo) * (1.f + Ec));
      unsigned short hb = f2bf(hv);
      hw0[0] = hb;
      *cgp = hb;
      cgp += HID;
      lds_barrier();
    }
  }
}

__global__ __launch_bounds__(256, 1) void lstm_hoist(
    const unsigned short* __restrict__ fAR, const unsigned short* __restrict__ fAL,
    const float* __restrict__ whh_rh, const float* __restrict__ whh_lh,
    const float* __restrict__ wih_ra, const float* __restrict__ whh_ra,
    const float* __restrict__ wih_la, const float* __restrict__ whh_la,
    const unsigned short* __restrict__ preR, const unsigned short* __restrict__ preL,
    const float* __restrict__ b1i, const float* __restrict__ b1h,
    const float* __restrict__ b3i, const float* __restrict__ b3h,
    unsigned short* __restrict__ combined) {
  __shared__ __align__(16) unsigned short A0[2304];
  __shared__ __align__(16) unsigned short A1[2304];
  int blk = blockIdx.x;
  int wave = threadIdx.x >> 6;
  if (blk < 64) {           // hands: 8 tiles x 4 r-instances x 2 sides
    int lr = blk >> 5, inst = blk & 31, tile = inst >> 2, r = inst & 3;
    const unsigned short* pp = (lr ? preL : preR) + (size_t)inst * 512 * 1024;
    const float* wq = lr ? whh_lh : whh_rh;
    unsigned short* cmb = combined + (lr ? 96 : 0);
    int b0 = tile * 16 + r;
    if (r == 0)
      lstm_core1<64, 2, 72, 16, 0, 0, true, 0, 4>(
          A0, A1, wq, nullptr, nullptr, nullptr, nullptr, pp, cmb, b0, 0, wave * 16);
    else if (r == 1)
      lstm_core1<64, 2, 72, 16, 0, 0, true, 1, 4>(
          A0, A1, wq, nullptr, nullptr, nullptr, nullptr, pp, cmb, b0, 0, wave * 16);
    else if (r == 2)
      lstm_core1<64, 2, 72, 16, 0, 0, true, 2, 4>(
          A0, A1, wq, nullptr, nullptr, nullptr, nullptr, pp, cmb, b0, 0, wave * 16);
    else
      lstm_core1<64, 2, 72, 16, 0, 0, true, 3, 4>(
          A0, A1, wq, nullptr, nullptr, nullptr, nullptr, pp, cmb, b0, 0, wave * 16);
  } else {                  // arms: 8 tiles x 2 r-instances x 2 sides
    int a = blk - 64;
    int la = a >> 4, rem = a & 15, tl = rem >> 1, r = rem & 1;
    const unsigned short* fpz = (la ? fAL : fAR) + (size_t)tl * 512 * 256;
    const float* wxp = la ? wih_la : wih_ra;
    const float* wqp = la ? whh_la : whh_ra;
    const float* bip = la ? b3i : b1i;
    const float* bhp = la ? b3h : b1h;
    unsigned short* cmb = combined + (la ? 160 : 64);
    int mrow0 = (wave >> 1) * 16, j0 = (wave & 1) * 16;
    if (r == 0)
      lstm_core1<32, 2, 72, 32, 1, 32, false, 0, 2>(
          A0, A1, wqp, wxp, bip, bhp, fpz, nullptr, cmb,
          tl * 16 + 0, mrow0, j0);
    else
      lstm_core1<32, 2, 72, 32, 1, 32, false, 1, 2>(
          A0, A1, wqp, wxp, bip, bhp, fpz, nullptr, cmb,
          tl * 16 + 1, mrow0, j0);
  }
}

// ---------------- K2 (fallback): RV=4 core --------------------------------

template <int H, int CH, int STR, int MB, int SCH, int HOFF, int RV>
__device__ __forceinline__ void lstm_core_fb(
    unsigned short* __restrict__ Ab0, unsigned short* __restrict__ Ab1,
    const unsigned short* __restrict__ Bt,
    const float* __restrict__ bi, const float* __restrict__ bh,
    const unsigned short* __restrict__ featp,
    unsigned short* __restrict__ combbase,
    int b0, int mrow0, int j0) {
  constexpr int K = CH * 32;
  constexpr int XSH = MB * SCH * 8;
  constexpr int JQ = H / 4;
  constexpr int VR = MB;
  int tid = threadIdx.x;
  int lane = tid & 63, n = lane & 15, quad = lane >> 4;

  short8 Vb[4][CH];
  float bias[4];
#pragma unroll
  for (int q = 0; q < 4; ++q) {
    int g = q * H + j0 + n;
    bias[q] = (bi[g] + bh[g]) * ((q == 2) ? NL2E2 : NL2E);
#pragma unroll
    for (int c = 0; c < CH; ++c)
      Vb[q][c] = *(const short8*)(Bt + (size_t)g * K + c * 32 + quad * 8);
  }

  for (int i = tid; i < MB * STR; i += 256) { Ab0[i] = 0; Ab1[i] = 0; }
  __syncthreads();

  bool st = tid < MB * SCH;
  int sm = SCH ? tid / SCH : 0, sc8 = SCH ? tid % SCH : 0;
  unsigned short* xd0 = Ab0 + sm * STR + sc8 * 8;
  unsigned short* xd1 = Ab1 + sm * STR + sc8 * 8;
  const unsigned short* fp = featp + tid * 8;
  short8 xE, xO;
  if (st) {
    *(short8*)xd0 = *(const short8*)fp;
    xO = *(const short8*)(fp + XSH);
    xE = *(const short8*)(fp + 2 * (size_t)XSH);
  }
  fp += 3 * (size_t)XSH;

  float4v cc = {0.f, 0.f, 0.f, 0.f};
  __syncthreads();

  const unsigned short* ard0 = Ab0 + (mrow0 + n) * STR;
  const unsigned short* ard1 = Ab1 + (mrow0 + n) * STR;
  unsigned short* hw0 = Ab0 + (mrow0 + quad * 4) * STR + HOFF + j0 + n;
  unsigned short* hw1 = Ab1 + (mrow0 + quad * 4) * STR + HOFF + j0 + n;

  int vi = tid / JQ, fjq = tid % JQ;
  bool fon = tid < VR * JQ;
  int fm = vi;
  const unsigned short* fl0 = Ab0 + fm * STR + HOFF + fjq * 4;
  const unsigned short* fl1 = Ab1 + fm * STR + HOFF + fjq * 4;
  unsigned short* cfp = combbase + ((size_t)(b0 + vi) * TLEN) * HID + fjq * 4;

#define ACT_FB(hw)                                                            \
  _Pragma("unroll")                                                           \
  for (int r = 0; r < RV; ++r) {                                              \
    float Ei = exp2i(acc[0][r]);                                              \
    float Ef = exp2i(acc[1][r]);                                              \
    float Eg = exp2i(acc[2][r]);                                              \
    float Eo = exp2i(acc[3][r]);                                              \
    float gf = __builtin_amdgcn_rcpf(1.f + Ef);                               \
    float ig = (1.f - Eg) * __builtin_amdgcn_rcpf((1.f + Ei) * (1.f + Eg));   \
    float cv = fmaf(gf, cc[r], ig);                                           \
    cc[r] = cv;                                                               \
    float Ec = exp2i(cv * NL2E2);                                             \
    float hv = (1.f - Ec) * __builtin_amdgcn_rcpf((1.f + Eo) * (1.f + Ec));   \
    (hw)[r * STR] = f2bf(hv);                                                 \
  }

  for (int tt = 0; tt < TLEN; tt += 2) {
    {
      const int t = tt;
      if (fon && t > 0) {
        *(uint2*)cfp = *(const uint2*)fl0;
        cfp += HID;
      }
      short8 Va[CH];
#pragma unroll
      for (int c = 0; c < CH; ++c)
        Va[c] = *(const short8*)(ard0 + c * 32 + quad * 8);
      float4v acc[4];
#pragma unroll
      for (int q = 0; q < 4; ++q)
        acc[q] = (float4v){bias[q], bias[q], bias[q], bias[q]};
#pragma unroll
      for (int q = 0; q < 4; ++q)
#pragma unroll
        for (int c = 0; c < CH; ++c)
          acc[q] = __builtin_amdgcn_mfma_f32_16x16x32_bf16(Va[c], Vb[q][c], acc[q], 0, 0, 0);
      if (st) {
        *(short8*)xd1 = xO;
        if (t + 3 < TLEN) xO = *(const short8*)fp;
      }
      fp += XSH;
      ACT_FB(hw1)
      lds_barrier();
    }
    {
      const int t = tt + 1;
      if (fon) {
        *(uint2*)cfp = *(const uint2*)fl1;
        cfp += HID;
      }
      short8 Va[CH];
#pragma unroll
      for (int c = 0; c < CH; ++c)
        Va[c] = *(const short8*)(ard1 + c * 32 + quad * 8);
      float4v acc[4];
#pragma unroll
      for (int q = 0; q < 4; ++q)
        acc[q] = (float4v){bias[q], bias[q], bias[q], bias[q]};
#pragma unroll
      for (int q = 0; q < 4; ++q)
#pragma unroll
        for (int c = 0; c < CH; ++c)
          acc[q] = __builtin_amdgcn_mfma_f32_16x16x32_bf16(Va[c], Vb[q][c], acc[q], 0, 0, 0);
      if (st) {
        if (t + 1 < TLEN) *(short8*)xd0 = xE;
        if (t + 3 < TLEN) xE = *(const short8*)fp;
      }
      fp += XSH;
      ACT_FB(hw0)
      lds_barrier();
    }
  }
  if (fon) *(uint2*)cfp = *(const uint2*)fl0;
#undef ACT_FB
}

__global__ __launch_bounds__(256, 1) void lstm_fb(
    const unsigned short* __restrict__ fHR, const unsigned short* __restrict__ fHL,
    const unsigned short* __restrict__ fAR, const unsigned short* __restrict__ fAL,
    const unsigned short* __restrict__ btA_r, const unsigned short* __restrict__ btA_l,
    const unsigned short* __restrict__ btArm_r, const unsigned short* __restrict__ btArm_l,
    const float* __restrict__ b0i, const float* __restrict__ b0h,
    const float* __restrict__ b1i, const float* __restrict__ b1h,
    const float* __restrict__ b2i, const float* __restrict__ b2h,
    const float* __restrict__ b3i, const float* __restrict__ b3h,
    unsigned short* __restrict__ combined) {
  __shared__ __align__(16) unsigned short A0[2304];
  __shared__ __align__(16) unsigned short A1[2304];
  int blk = blockIdx.x;
  int wave = threadIdx.x >> 6;
  if (blk < 16) {
    int lr = blk >> 3, tl = blk & 7;
    lstm_core_fb<64, 4, 136, 16, 6, 64, 4>(
        A0, A1, lr ? btA_l : btA_r, lr ? b2i : b0i, lr ? b2h : b0h,
        (lr ? fHL : fHR) + (size_t)tl * 512 * 768,
        combined + (lr ? 96 : 0), tl * 16, 0, wave * 16);
  } else {
    int a = blk - 16;
    int la = a >> 2, tl = a & 3;
    lstm_core_fb<32, 2, 72, 32, 1, 32, 4>(
        A0, A1, la ? btArm_l : btArm_r, la ? b3i : b1i, la ? b3h : b1h,
        (la ? fAL : fAR) + (size_t)tl * 512 * 256,
        combined + (la ? 160 : 64), tl * 32, (wave >> 1) * 16, (wave & 1) * 16);
  }
}

// ---------------- K3: attention + FC (512 threads, bf16 combined) ---------

__global__ __launch_bounds__(512) void attn_kernel(const unsigned short* __restrict__ combined,
                                                   const float* __restrict__ att_w,
                                                   const float* __restrict__ fc_w,
                                                   const float* __restrict__ fc_b,
                                                   float* __restrict__ dout) {
  __shared__ float sc[TLEN];
  __shared__ float aw[HID];
  __shared__ float pctx[8][HID];
  __shared__ float ctx[HID];
  __shared__ float red[8];
  int b = blockIdx.x, tid = threadIdx.x;
  int lane = tid & 63, wave = tid >> 6;
  const unsigned short* cb = combined + (size_t)b * TLEN * HID;
  if (tid < HID) aw[tid] = att_w[tid];
  __syncthreads();
  float a0 = aw[lane], a1 = aw[lane + 64], a2 = aw[lane + 128];

  int t0 = wave * 64;
  for (int t = t0; t < t0 + 64; t += 2) {
    const unsigned short* r0 = cb + (size_t)t * HID;
    const unsigned short* r1 = r0 + HID;
    float p0 = a0 * bf2f(r0[lane]) + a1 * bf2f(r0[lane + 64]) + a2 * bf2f(r0[lane + 128]);
    float p1 = a0 * bf2f(r1[lane]) + a1 * bf2f(r1[lane + 64]) + a2 * bf2f(r1[lane + 128]);
#pragma unroll
    for (int o = 32; o; o >>= 1) {
      p0 += __shfl_xor(p0, o, 64);
      p1 += __shfl_xor(p1, o, 64);
    }
    if (lane == 0) { sc[t] = p0; sc[t + 1] = p1; }
  }
  __syncthreads();

  float e = sc[tid];
  float lmax = e;
#pragma unroll
  for (int o = 32; o; o >>= 1) lmax = fmaxf(lmax, __shfl_xor(lmax, o, 64));
  if (lane == 0) red[wave] = lmax;
  __syncthreads();
  float m = red[0];
#pragma unroll
  for (int w = 1; w < 8; ++w) m = fmaxf(m, red[w]);
  __syncthreads();
  float ex = __expf(e - m);
  float ls = ex;
#pragma unroll
  for (int o = 32; o; o >>= 1) ls += __shfl_xor(ls, o, 64);
  if (lane == 0) red[wave] = ls;
  __syncthreads();
  float S = red[0];
#pragma unroll
  for (int w = 1; w < 8; ++w) S += red[w];
  float wgt = ex / S;
  sc[tid] = wgt;
  dout[BATCH * NC + b * TLEN + tid] = wgt;  // weights (B,T,1)
  __syncthreads();

#pragma unroll
  for (int p = 0; p < 3; ++p) {
    int h = p * 64 + lane;
    float c0 = 0.f, c1 = 0.f, c2 = 0.f, c3 = 0.f;
    for (int t = t0; t < t0 + 64; t += 4) {
      c0 += sc[t] * bf2f(cb[(size_t)t * HID + h]);
      c1 += sc[t + 1] * bf2f(cb[(size_t)(t + 1) * HID + h]);
      c2 += sc[t + 2] * bf2f(cb[(size_t)(t + 2) * HID + h]);
      c3 += sc[t + 3] * bf2f(cb[(size_t)(t + 3) * HID + h]);
    }
    pctx[wave][h] = (c0 + c1) + (c2 + c3);
  }
  __syncthreads();
  if (tid < HID) {
    float s = pctx[0][tid];
#pragma unroll
    for (int w = 1; w < 8; ++w) s += pctx[w][tid];
    ctx[tid] = s;
  }
  __syncthreads();

  if (tid < NC) {
    const float* wr = fc_w + (size_t)tid * HID;
    float s0 = fc_b[tid], s1 = 0.f, s2 = 0.f, s3 = 0.f;
#pragma unroll
    for (int h = 0; h < HID; h += 4) {
      s0 += ctx[h] * wr[h];
      s1 += ctx[h + 1] * wr[h + 1];
      s2 += ctx[h + 2] * wr[h + 2];
      s3 += ctx[h + 3] * wr[h + 3];
    }
    dout[b * NC + tid] = (s0 + s1) + (s2 + s3);  // logits (B,250)
  }
}

// ---------------- launcher ----------------

extern "C" void kernel_launch(void* const* d_in, const int* in_sizes, int n_in,
                              void* d_out, int out_size, void* d_ws, size_t ws_size,
                              hipStream_t stream) {
  const float* x = (const float*)d_in[0];
  const float* wih_rh = (const float*)d_in[1];
  const float* whh_rh = (const float*)d_in[2];
  const float* bih_rh = (const float*)d_in[3];
  const float* bhh_rh = (const float*)d_in[4];
  const float* wih_ra = (const float*)d_in[5];
  const float* whh_ra = (const float*)d_in[6];
  const float* bih_ra = (const float*)d_in[7];
  const float* bhh_ra = (const float*)d_in[8];
  const float* wih_lh = (const float*)d_in[9];
  const float* whh_lh = (const float*)d_in[10];
  const float* bih_lh = (const float*)d_in[11];
  const float* bhh_lh = (const float*)d_in[12];
  const float* wih_la = (const float*)d_in[13];
  const float* whh_la = (const float*)d_in[14];
  const float* bih_la = (const float*)d_in[15];
  const float* bhh_la = (const float*)d_in[16];
  const float* att_w = (const float*)d_in[17];
  const float* fc_w = (const float*)d_in[18];
  const float* fc_b = (const float*)d_in[19];

  const size_t SZ_COMB   = (size_t)BATCH * TLEN * HID * 2;   // 25,165,824 (bf16)
  const size_t SZ_FARM_H = (size_t)8 * TLEN * 32 * 8 * 2;    // 2,097,152 (hoist)
  const size_t SZ_FARM_F = (size_t)4 * TLEN * 32 * 8 * 2;    // 1,048,576 (fb)
  const size_t SZ_F64    = (size_t)8 * TLEN * 16 * 64 * 2;   // 8,388,608
  const size_t SZ_F48    = (size_t)8 * TLEN * 16 * 48 * 2;   // 6,291,456
  const size_t SZ_PRE    = (size_t)32 * TLEN * 1024 * 2;     // 33,554,432
  const size_t NEED_FULL = SZ_COMB + 2 * SZ_FARM_H + 2 * SZ_F64 + 2 * SZ_PRE;
  bool hoist = ws_size >= NEED_FULL;

  char* p = (char*)d_ws;
  unsigned short* combined = (unsigned short*)p; p += SZ_COMB;
  unsigned short *fAR, *fAL;
  unsigned short *fHR, *fHL, *preR = nullptr, *preL = nullptr;
  unsigned short *btA_r = nullptr, *btA_l = nullptr, *btArm_r = nullptr, *btArm_l = nullptr;
  if (hoist) {
    fAR = (unsigned short*)p; p += SZ_FARM_H;
    fAL = (unsigned short*)p; p += SZ_FARM_H;
    fHR = (unsigned short*)p; p += SZ_F64;
    fHL = (unsigned short*)p; p += SZ_F64;
    preR = (unsigned short*)p; p += SZ_PRE;
    preL = (unsigned short*)p; p += SZ_PRE;
  } else {
    fAR = (unsigned short*)p; p += SZ_FARM_F;
    fAL = (unsigned short*)p; p += SZ_FARM_F;
    fHR = (unsigned short*)p; p += SZ_F48;
    fHL = (unsigned short*)p; p += SZ_F48;
    btA_r = (unsigned short*)p; p += 65536;
    btA_l = (unsigned short*)p; p += 65536;
    btArm_r = (unsigned short*)p; p += 16384;
    btArm_l = (unsigned short*)p;
  }

  prep_kernel<<<dim3((BATCH * TLEN + 255) / 256), 256, 0, stream>>>(
      x, fHR, fHL, fAR, fAL, hoist ? 1 : 0);
  if (hoist) {
    pregemm_kernel<<<dim3(256), 256, 0, stream>>>(
        fHR, fHL, wih_rh, wih_lh, bih_rh, bhh_rh, bih_lh, bhh_lh, preR, preL);
    lstm_hoist<<<dim3(96), 256, 0, stream>>>(
        fAR, fAL, whh_rh, whh_lh, wih_ra, whh_ra, wih_la, whh_la,
        preR, preL, bih_ra, bhh_ra, bih_la, bhh_la, combined);
  } else {
    pack_kernel<<<dim3(4), 256, 0, stream>>>(
        wih_rh, whh_rh, wih_ra, whh_ra, wih_lh, whh_lh, wih_la, whh_la,
        btA_r, btA_l, btArm_r, btArm_l);
    lstm_fb<<<dim3(24), 256, 0, stream>>>(
        fHR, fHL, fAR, fAL, btA_r, btA_l, btArm_r, btArm_l,
        bih_rh, bhh_rh, bih_ra, bhh_ra, bih_lh, bhh_lh, bih_la, bhh_la, combined);
  }
  attn_kernel<<<dim3(BATCH), 512, 0, stream>>>(combined, att_w, fc_w, fc_b, (float*)d_out);
}

// Round 9
// 386.888 us; speedup vs baseline: 1.0714x; 1.0714x over previous
//
#include <hip/hip_runtime.h>
#include <math.h>

#define BATCH 128
#define TLEN 512
#define XF 266
#define HID 192
#define NC 250

typedef __attribute__((ext_vector_type(8))) short short8;
typedef __attribute__((ext_vector_type(4))) float float4v;

#define NL2E  -1.4426950408889634f
#define NL2E2 -2.8853900817779268f

// fp32 -> bf16 (RNE)
__device__ __forceinline__ unsigned short f2bf(float f) {
  unsigned u = __float_as_uint(f);
  u += 0x7FFF + ((u >> 16) & 1);
  return (unsigned short)(u >> 16);
}
__device__ __forceinline__ float bf2f(unsigned short s) {
  return __uint_as_float(((unsigned)s) << 16);
}

// single-instruction exp2 (v_exp_f32)
__device__ __forceinline__ float exp2i(float x) {
#if __has_builtin(__builtin_amdgcn_exp2f)
  return __builtin_amdgcn_exp2f(x);
#else
  float r;
  asm("v_exp_f32 %0, %1" : "=v"(r) : "v"(x));
  return r;
#endif
}

// LDS-only barrier: does NOT drain vmcnt.
__device__ __forceinline__ void lds_barrier() {
  asm volatile("s_waitcnt lgkmcnt(0)\n\ts_barrier" ::: "memory");
}

// ---------------- K1: feature prep (VECTOR STORES) ------------------------
// hoist: hands [tile8][t][row16][64], tile=b>>4, row=b&15 (plain rows)
//        arms  [tile8][t][m32][8],  tile=b>>4, va=b&15,
//                row (va>>3)*16 + ((va&7)>>1)*4 + (va&1)
// fb: hands [tile8][t][m16][48] row=b&15; arms [tile4][t][m32][8] row=b&31

template <int HS>
__device__ __forceinline__ void norm_hand_s(const float* __restrict__ xp,
                                            unsigned short* __restrict__ fp,
                                            int p0, int refp) {
  float rx = xp[2 * refp], ry = xp[2 * refp + 1];
  float px[21], py[21];
  float minx = 1e30f, maxx = -1e30f, miny = 1e30f, maxy = -1e30f;
#pragma unroll
  for (int i = 0; i < 21; ++i) {
    float ax = xp[2 * (p0 + i)] - rx;
    float ay = xp[2 * (p0 + i) + 1] - ry;
    px[i] = ax; py[i] = ay;
    minx = fminf(minx, ax); maxx = fmaxf(maxx, ax);
    miny = fminf(miny, ay); maxy = fmaxf(maxy, ay);
  }
  float s = fmaxf(maxx - minx, maxy - miny);
  if (s == 0.f) s = 1.f;
  float inv = 1.f / s;
#pragma unroll
  for (int j = 0; j < HS / 8; ++j) {
    short8 v;
#pragma unroll
    for (int k = 0; k < 8; ++k) {
      int i = 8 * j + k;  // compile-time constant after unroll
      float val = (i < 42) ? ((i & 1) ? py[i >> 1] : px[i >> 1]) * inv : 0.f;
      v[k] = (short)f2bf(val);
    }
    *(short8*)(fp + 8 * j) = v;
  }
}

__device__ __forceinline__ void norm_arm_s(const float* __restrict__ xp,
                                           unsigned short* __restrict__ fp,
                                           int a, int b, int c) {
  float rx = xp[0], ry = xp[1];
  float x0 = xp[2 * a] - rx, y0 = xp[2 * a + 1] - ry;
  float x1 = xp[2 * b] - rx, y1 = xp[2 * b + 1] - ry;
  float x2 = xp[2 * c] - rx, y2 = xp[2 * c + 1] - ry;
  float w = fmaxf(fmaxf(x0, x1), x2) - fminf(fminf(x0, x1), x2);
  float h = fmaxf(fmaxf(y0, y1), y2) - fminf(fminf(y0, y1), y2);
  float s = fmaxf(w, h);
  if (s == 0.f) s = 1.f;
  float inv = 1.f / s;
  short8 v;
  v[0] = (short)f2bf(x0 * inv); v[1] = (short)f2bf(y0 * inv);
  v[2] = (short)f2bf(x1 * inv); v[3] = (short)f2bf(y1 * inv);
  v[4] = (short)f2bf(x2 * inv); v[5] = (short)f2bf(y2 * inv);
  v[6] = 0; v[7] = 0;
  *(short8*)fp = v;
}

__global__ __launch_bounds__(256) void prep_kernel(
    const float* __restrict__ x,
    unsigned short* __restrict__ fHR, unsigned short* __restrict__ fHL,
    unsigned short* __restrict__ fAR, unsigned short* __restrict__ fAL,
    int mode) {
  int idx = blockIdx.x * 256 + threadIdx.x;
  if (idx >= BATCH * TLEN) return;
  int b = idx >> 9, t = idx & 511;
  const float* xp = x + (size_t)idx * XF;
  if (mode) {
    size_t hoff = (((size_t)(b >> 4) * TLEN + t) * 16 + (b & 15)) * 64;
    int va = b & 15;
    int rowa = (va >> 3) * 16 + ((va & 7) >> 1) * 4 + (va & 1);
    size_t aoff = (((size_t)(b >> 4) * TLEN + t) * 32 + rowa) * 8;
    norm_hand_s<64>(xp, fHR + hoff, 112, 10);  // right hand, ref pt 10
    norm_hand_s<64>(xp, fHL + hoff, 91, 9);    // left hand, ref pt 9
    norm_arm_s(xp, fAR + aoff, 6, 8, 10);      // right arm
    norm_arm_s(xp, fAL + aoff, 5, 7, 9);       // left arm
  } else {
    size_t hoff = (((size_t)(b >> 4) * TLEN + t) * 16 + (b & 15)) * 48;
    size_t aoff = (((size_t)(b >> 5) * TLEN + t) * 32 + (b & 31)) * 8;
    norm_hand_s<48>(xp, fHR + hoff, 112, 10);
    norm_hand_s<48>(xp, fHL + hoff, 91, 9);
    norm_arm_s(xp, fAR + aoff, 6, 8, 10);
    norm_arm_s(xp, fAL + aoff, 5, 7, 9);
  }
}

// ---------------- K1b: weight packing (FB MODE ONLY) ----------------------

__global__ __launch_bounds__(256) void pack_kernel(
    const float* __restrict__ wi_rh, const float* __restrict__ wh_rh,
    const float* __restrict__ wi_ra, const float* __restrict__ wh_ra,
    const float* __restrict__ wi_lh, const float* __restrict__ wh_lh,
    const float* __restrict__ wi_la, const float* __restrict__ wh_la,
    unsigned short* __restrict__ btA_r, unsigned short* __restrict__ btA_l,
    unsigned short* __restrict__ btArm_r, unsigned short* __restrict__ btArm_l) {
  int blk = blockIdx.x, tid = threadIdx.x;
  if (blk < 2) {
    const float* wi = blk ? wi_lh : wi_rh;
    const float* wh = blk ? wh_lh : wh_rh;
    unsigned short* dst = blk ? btA_l : btA_r;
    for (int i = tid; i < 256 * 128; i += 256) {
      int g = i >> 7, k = i & 127;
      float s = ((g >> 6) == 2) ? NL2E2 : NL2E;
      float v = (k < 42) ? wi[g * 42 + k] : (k < 64 ? 0.f : wh[g * 64 + (k - 64)]);
      dst[i] = f2bf(v * s);
    }
  } else {
    const float* wi = (blk == 3) ? wi_la : wi_ra;
    const float* wh = (blk == 3) ? wh_la : wh_ra;
    unsigned short* dst = (blk == 3) ? btArm_l : btArm_r;
    for (int i = tid; i < 128 * 64; i += 256) {
      int g = i >> 6, k = i & 63;
      float s = ((g >> 5) == 2) ? NL2E2 : NL2E;
      float v = (k < 6) ? wi[g * 6 + k] : (k < 32 ? 0.f : wh[g * 32 + (k - 32)]);
      dst[i] = f2bf(v * s);
    }
  }
}

// ---------------- K1c: input-projection pre-GEMM (hoist mode) ------------
// Both-side-coalesced pre layout. Instance = (tile, r): batches
// tile*16 + quad*4 + r. Per (inst,t) 1024 shorts:
//   off = jt*256 + quad*64 + n*4 + gate   (4 gates packed in one uint2)

__global__ __launch_bounds__(256, 1) void pregemm_kernel(
    const unsigned short* __restrict__ f64R, const unsigned short* __restrict__ f64L,
    const float* __restrict__ wiR, const float* __restrict__ wiL,
    const float* __restrict__ biR, const float* __restrict__ bhR,
    const float* __restrict__ biL, const float* __restrict__ bhL,
    unsigned short* __restrict__ preR, unsigned short* __restrict__ preL) {
  int bx = blockIdx.x;
  int lr = bx >> 7, tile = (bx >> 4) & 7, tc = bx & 15;
  const unsigned short* f64 = lr ? f64L : f64R;
  const float* wi = lr ? wiL : wiR;
  const float* bi = lr ? biL : biR;
  const float* bh = lr ? bhL : bhR;
  unsigned short* pre = lr ? preL : preR;
  int tid = threadIdx.x, lane = tid & 63;
  int jg = tid >> 6, n = lane & 15, quad = lane >> 4;

  short8 Vb[4][2];
  float bias[4];
#pragma unroll
  for (int q = 0; q < 4; ++q) {
    float sq = (q == 2) ? NL2E2 : NL2E;
    int g = q * 64 + jg * 16 + n;
    bias[q] = (bi[g] + bh[g]) * sq;
#pragma unroll
    for (int c = 0; c < 2; ++c) {
      short8 vb;
#pragma unroll
      for (int s = 0; s < 8; ++s) {
        int k = c * 32 + quad * 8 + s;
        vb[s] = (short)f2bf(k < 42 ? wi[g * 42 + k] * sq : 0.f);
      }
      Vb[q][c] = vb;
    }
  }

  const unsigned short* ap =
      f64 + ((size_t)(tile * 512 + tc * 32) * 16 + n) * 64 + quad * 8;
  short8 VaC0 = *(const short8*)ap;
  short8 VaC1 = *(const short8*)(ap + 32);
  ap += 1024;
  unsigned short* pb = pre + ((size_t)(tile * 4) * 512 + tc * 32) * 1024 +
                       jg * 256 + quad * 64 + n * 4;
  for (int i = 0; i < 32; ++i) {
    short8 VaN0, VaN1;
    if (i + 1 < 32) {
      VaN0 = *(const short8*)ap;
      VaN1 = *(const short8*)(ap + 32);
    }
    ap += 1024;
    float4v acc[4];
#pragma unroll
    for (int q = 0; q < 4; ++q) {
      acc[q] = (float4v){bias[q], bias[q], bias[q], bias[q]};
      acc[q] = __builtin_amdgcn_mfma_f32_16x16x32_bf16(VaC0, Vb[q][0], acc[q], 0, 0, 0);
      acc[q] = __builtin_amdgcn_mfma_f32_16x16x32_bf16(VaC1, Vb[q][1], acc[q], 0, 0, 0);
    }
#pragma unroll
    for (int r = 0; r < 4; ++r) {
      uint2 u;
      u.x = (unsigned)f2bf(acc[0][r]) | ((unsigned)f2bf(acc[1][r]) << 16);
      u.y = (unsigned)f2bf(acc[2][r]) | ((unsigned)f2bf(acc[3][r]) << 16);
      *(uint2*)(pb + (size_t)r * (512 * 1024)) = u;
    }
    pb += 1024;
    VaC0 = VaN0;
    VaC1 = VaN1;
  }
}

// ---------------- K2 (hoist): RV=1 MFMA LSTM recurrence (round-5 core) ----
// One cell per lane per step; 4-wave instance; 1 barrier/step. This is the
// empirical local optimum (891 cy/step): wider waves (16 MFMA/wave),
// single-wave (32 MFMA/wave), and split/persistent accumulators all
// regressed (R4/R6/R8).

template <int H, int CH, int STR, int MB, int SCH, int HOFF, bool HOIST, int RSEL, int BQS>
__device__ __forceinline__ void lstm_core1(
    unsigned short* __restrict__ Ab0, unsigned short* __restrict__ Ab1,
    const float* __restrict__ wq,   // hands: whh (4H x H); arms: whh
    const float* __restrict__ wx,   // arms: wih (4H x 6); hands unused
    const float* __restrict__ bi, const float* __restrict__ bh,  // arms only
    const unsigned short* __restrict__ featp,   // arms (tile base)
    const unsigned short* __restrict__ prep_,   // hands (instance base)
    unsigned short* __restrict__ combbase,      // combined + col offset
    int b0, int mrow0, int j0) {
  constexpr int XSH = MB * SCH * 8;
  int tid = threadIdx.x;
  int lane = tid & 63, n = lane & 15, quad = lane >> 4;

  // B fragments inline-converted from f32 (pre-scaled by -log2e / -2log2e)
  short8 Vb[4][CH];
  float bias[4];
#pragma unroll
  for (int q = 0; q < 4; ++q) {
    float sq = (q == 2) ? NL2E2 : NL2E;
    int g = q * H + j0 + n;
    if (!HOIST) bias[q] = (bi[g] + bh[g]) * sq;
#pragma unroll
    for (int c = 0; c < CH; ++c) {
      short8 vb;
#pragma unroll
      for (int s = 0; s < 8; ++s) {
        int k = c * 32 + quad * 8 + s;
        float v;
        if (HOIST) {
          v = wq[(size_t)g * H + k];                       // K == H (h-only)
        } else {
          v = (k < 6) ? wx[g * 6 + k]
                      : (k >= 32 ? wq[g * 32 + (k - 32)] : 0.f);
        }
        vb[s] = (short)f2bf(v * sq);
      }
      Vb[q][c] = vb;
    }
  }

  for (int i = tid; i < MB * STR; i += 256) { Ab0[i] = 0; Ab1[i] = 0; }
  __syncthreads();  // zero-init visible before staging writes

  // x staging (arms): static even/odd regs
  bool st = false;
  unsigned short *xd0 = nullptr, *xd1 = nullptr;
  const unsigned short* fp = nullptr;
  short8 xE, xO;
  if (!HOIST) {
    st = tid < MB * SCH;
    xd0 = Ab0 + tid * STR;
    xd1 = Ab1 + tid * STR;
    fp = featp + tid * 8;
    if (st) {
      *(short8*)xd0 = *(const short8*)fp;            // feat[0] -> buf0
      xO = *(const short8*)(fp + XSH);               // feat[1]
      xE = *(const short8*)(fp + 2 * (size_t)XSH);   // feat[2]
    }
    fp += 3 * (size_t)XSH;
  }

  // packed-pre prefetch (hands): uint2 per step, static even/odd regs
  const unsigned short *ppE = nullptr, *ppO = nullptr;
  uint2 pE = {0, 0}, pO = {0, 0};
  if (HOIST) {
    const unsigned short* pp0 = prep_ + (size_t)(j0 >> 4) * 256 + quad * 64 + n * 4;
    pE = *(const uint2*)pp0;              // pre[0]
    pO = *(const uint2*)(pp0 + 1024);     // pre[1]
    ppE = pp0 + 2 * 1024;
    ppO = pp0 + 3 * 1024;
  }

  float cc = 0.f;
  __syncthreads();

  const unsigned short* ard0 = Ab0 + (mrow0 + n) * STR;
  const unsigned short* ard1 = Ab1 + (mrow0 + n) * STR;
  unsigned short* hw0 = Ab0 + (mrow0 + quad * 4 + RSEL) * STR + HOFF + j0 + n;
  unsigned short* hw1 = Ab1 + (mrow0 + quad * 4 + RSEL) * STR + HOFF + j0 + n;
  unsigned short* cgp = combbase +
      ((size_t)(b0 + (mrow0 >> 1) + quad * BQS) * TLEN) * HID + j0 + n;

  for (int tt = 0; tt < TLEN; tt += 2) {
    // ------- even step t = tt (reads buf0, writes h to buf1) -------------
    {
      const int t = tt;
      short8 Va[CH];
#pragma unroll
      for (int c = 0; c < CH; ++c)
        Va[c] = *(const short8*)(ard0 + c * 32 + quad * 8);

      float4v acc[4];
#pragma unroll
      for (int q = 0; q < 4; ++q) acc[q] = (float4v){0.f, 0.f, 0.f, 0.f};
      if (HOIST) {
        acc[0][RSEL] = __uint_as_float(pE.x << 16);
        acc[1][RSEL] = __uint_as_float(pE.x & 0xffff0000u);
        acc[2][RSEL] = __uint_as_float(pE.y << 16);
        acc[3][RSEL] = __uint_as_float(pE.y & 0xffff0000u);
        if (t + 2 < TLEN) pE = *(const uint2*)ppE;   // refill (pre[t+2])
        ppE += 2 * 1024;
      } else {
#pragma unroll
        for (int q = 0; q < 4; ++q) acc[q][RSEL] = bias[q];
      }
#pragma unroll
      for (int q = 0; q < 4; ++q)
#pragma unroll
        for (int c = 0; c < CH; ++c)
          acc[q] = __builtin_amdgcn_mfma_f32_16x16x32_bf16(Va[c], Vb[q][c], acc[q], 0, 0, 0);

      if (!HOIST) {
        if (st) {
          *(short8*)xd1 = xO;                          // feat[t+1] -> buf1
          if (t + 3 < TLEN) xO = *(const short8*)fp;   // feat[t+3]
        }
        fp += XSH;
      }

      float Ei = exp2i(acc[0][RSEL]);
      float Ef = exp2i(acc[1][RSEL]);
      float Eg = exp2i(acc[2][RSEL]);
      float Eo = exp2i(acc[3][RSEL]);
      float gf = __builtin_amdgcn_rcpf(1.f + Ef);
      float ig = (1.f - Eg) * __builtin_amdgcn_rcpf((1.f + Ei) * (1.f + Eg));
      float cv = fmaf(gf, cc, ig);
      cc = cv;
      float Ec = exp2i(cv * NL2E2);
      float hv = (1.f - Ec) * __builtin_amdgcn_rcpf((1.f + Eo) * (1.f + Ec));
      unsigned short hb = f2bf(hv);
      hw1[0] = hb;        // LDS for recurrence
      *cgp = hb;          // direct global store of combined
      cgp += HID;
      lds_barrier();
    }
    // ------- odd step t = tt+1 (reads buf1, writes h to buf0) ------------
    {
      const int t = tt + 1;
      short8 Va[CH];
#pragma unroll
      for (int c = 0; c < CH; ++c)
        Va[c] = *(const short8*)(ard1 + c * 32 + quad * 8);

      float4v acc[4];
#pragma unroll
      for (int q = 0; q < 4; ++q) acc[q] = (float4v){0.f, 0.f, 0.f, 0.f};
      if (HOIST) {
        acc[0][RSEL] = __uint_as_float(pO.x << 16);
        acc[1][RSEL] = __uint_as_float(pO.x & 0xffff0000u);
        acc[2][RSEL] = __uint_as_float(pO.y << 16);
        acc[3][RSEL] = __uint_as_float(pO.y & 0xffff0000u);
        if (t + 2 < TLEN) pO = *(const uint2*)ppO;   // refill (pre[t+2])
        ppO += 2 * 1024;
      } else {
#pragma unroll
        for (int q = 0; q < 4; ++q) acc[q][RSEL] = bias[q];
      }
#pragma unroll
      for (int q = 0; q < 4; ++q)
#pragma unroll
        for (int c = 0; c < CH; ++c)
          acc[q] = __builtin_amdgcn_mfma_f32_16x16x32_bf16(Va[c], Vb[q][c], acc[q], 0, 0, 0);

      if (!HOIST) {
        if (st) {
          if (t + 1 < TLEN) *(short8*)xd0 = xE;        // feat[t+1] -> buf0
          if (t + 3 < TLEN) xE = *(const short8*)fp;   // feat[t+3]
        }
        fp += XSH;
      }

      float Ei = exp2i(acc[0][RSEL]);
      float Ef = exp2i(acc[1][RSEL]);
      float Eg = exp2i(acc[2][RSEL]);
      float Eo = exp2i(acc[3][RSEL]);
      float gf = __builtin_amdgcn_rcpf(1.f + Ef);
      float ig = (1.f - Eg) * __builtin_amdgcn_rcpf((1.f + Ei) * (1.f + Eg));
      float cv = fmaf(gf, cc, ig);
      cc = cv;
      float Ec = exp2i(cv * NL2E2);
      float hv = (1.f - Ec) * __builtin_amdgcn_rcpf((1.f + Eo) * (1.f + Ec));
      unsigned short hb = f2bf(hv);
      hw0[0] = hb;
      *cgp = hb;
      cgp += HID;
      lds_barrier();
    }
  }
}

__global__ __launch_bounds__(256, 1) void lstm_hoist(
    const unsigned short* __restrict__ fAR, const unsigned short* __restrict__ fAL,
    const float* __restrict__ whh_rh, const float* __restrict__ whh_lh,
    const float* __restrict__ wih_ra, const float* __restrict__ whh_ra,
    const float* __restrict__ wih_la, const float* __restrict__ whh_la,
    const unsigned short* __restrict__ preR, const unsigned short* __restrict__ preL,
    const float* __restrict__ b1i, const float* __restrict__ b1h,
    const float* __restrict__ b3i, const float* __restrict__ b3h,
    unsigned short* __restrict__ combined) {
  __shared__ __align__(16) unsigned short A0[2304];
  __shared__ __align__(16) unsigned short A1[2304];
  int blk = blockIdx.x;
  int wave = threadIdx.x >> 6;
  if (blk < 64) {           // hands: 8 tiles x 4 r-instances x 2 sides
    int lr = blk >> 5, inst = blk & 31, tile = inst >> 2, r = inst & 3;
    const unsigned short* pp = (lr ? preL : preR) + (size_t)inst * 512 * 1024;
    const float* wq = lr ? whh_lh : whh_rh;
    unsigned short* cmb = combined + (lr ? 96 : 0);
    int b0 = tile * 16 + r;
    if (r == 0)
      lstm_core1<64, 2, 72, 16, 0, 0, true, 0, 4>(
          A0, A1, wq, nullptr, nullptr, nullptr, nullptr, pp, cmb, b0, 0, wave * 16);
    else if (r == 1)
      lstm_core1<64, 2, 72, 16, 0, 0, true, 1, 4>(
          A0, A1, wq, nullptr, nullptr, nullptr, nullptr, pp, cmb, b0, 0, wave * 16);
    else if (r == 2)
      lstm_core1<64, 2, 72, 16, 0, 0, true, 2, 4>(
          A0, A1, wq, nullptr, nullptr, nullptr, nullptr, pp, cmb, b0, 0, wave * 16);
    else
      lstm_core1<64, 2, 72, 16, 0, 0, true, 3, 4>(
          A0, A1, wq, nullptr, nullptr, nullptr, nullptr, pp, cmb, b0, 0, wave * 16);
  } else {                  // arms: 8 tiles x 2 r-instances x 2 sides
    int a = blk - 64;
    int la = a >> 4, rem = a & 15, tl = rem >> 1, r = rem & 1;
    const unsigned short* fpz = (la ? fAL : fAR) + (size_t)tl * 512 * 256;
    const float* wxp = la ? wih_la : wih_ra;
    const float* wqp = la ? whh_la : whh_ra;
    const float* bip = la ? b3i : b1i;
    const float* bhp = la ? b3h : b1h;
    unsigned short* cmb = combined + (la ? 160 : 64);
    int mrow0 = (wave >> 1) * 16, j0 = (wave & 1) * 16;
    if (r == 0)
      lstm_core1<32, 2, 72, 32, 1, 32, false, 0, 2>(
          A0, A1, wqp, wxp, bip, bhp, fpz, nullptr, cmb,
          tl * 16 + 0, mrow0, j0);
    else
      lstm_core1<32, 2, 72, 32, 1, 32, false, 1, 2>(
          A0, A1, wqp, wxp, bip, bhp, fpz, nullptr, cmb,
          tl * 16 + 1, mrow0, j0);
  }
}

// ---------------- K2 (fallback): RV=4 core --------------------------------

template <int H, int CH, int STR, int MB, int SCH, int HOFF, int RV>
__device__ __forceinline__ void lstm_core_fb(
    unsigned short* __restrict__ Ab0, unsigned short* __restrict__ Ab1,
    const unsigned short* __restrict__ Bt,
    const float* __restrict__ bi, const float* __restrict__ bh,
    const unsigned short* __restrict__ featp,
    unsigned short* __restrict__ combbase,
    int b0, int mrow0, int j0) {
  constexpr int K = CH * 32;
  constexpr int XSH = MB * SCH * 8;
  constexpr int JQ = H / 4;
  constexpr int VR = MB;
  int tid = threadIdx.x;
  int lane = tid & 63, n = lane & 15, quad = lane >> 4;

  short8 Vb[4][CH];
  float bias[4];
#pragma unroll
  for (int q = 0; q < 4; ++q) {
    int g = q * H + j0 + n;
    bias[q] = (bi[g] + bh[g]) * ((q == 2) ? NL2E2 : NL2E);
#pragma unroll
    for (int c = 0; c < CH; ++c)
      Vb[q][c] = *(const short8*)(Bt + (size_t)g * K + c * 32 + quad * 8);
  }

  for (int i = tid; i < MB * STR; i += 256) { Ab0[i] = 0; Ab1[i] = 0; }
  __syncthreads();

  bool st = tid < MB * SCH;
  int sm = SCH ? tid / SCH : 0, sc8 = SCH ? tid % SCH : 0;
  unsigned short* xd0 = Ab0 + sm * STR + sc8 * 8;
  unsigned short* xd1 = Ab1 + sm * STR + sc8 * 8;
  const unsigned short* fp = featp + tid * 8;
  short8 xE, xO;
  if (st) {
    *(short8*)xd0 = *(const short8*)fp;
    xO = *(const short8*)(fp + XSH);
    xE = *(const short8*)(fp + 2 * (size_t)XSH);
  }
  fp += 3 * (size_t)XSH;

  float4v cc = {0.f, 0.f, 0.f, 0.f};
  __syncthreads();

  const unsigned short* ard0 = Ab0 + (mrow0 + n) * STR;
  const unsigned short* ard1 = Ab1 + (mrow0 + n) * STR;
  unsigned short* hw0 = Ab0 + (mrow0 + quad * 4) * STR + HOFF + j0 + n;
  unsigned short* hw1 = Ab1 + (mrow0 + quad * 4) * STR + HOFF + j0 + n;

  int vi = tid / JQ, fjq = tid % JQ;
  bool fon = tid < VR * JQ;
  int fm = vi;
  const unsigned short* fl0 = Ab0 + fm * STR + HOFF + fjq * 4;
  const unsigned short* fl1 = Ab1 + fm * STR + HOFF + fjq * 4;
  unsigned short* cfp = combbase + ((size_t)(b0 + vi) * TLEN) * HID + fjq * 4;

#define ACT_FB(hw)                                                            \
  _Pragma("unroll")                                                           \
  for (int r = 0; r < RV; ++r) {                                              \
    float Ei = exp2i(acc[0][r]);                                              \
    float Ef = exp2i(acc[1][r]);                                              \
    float Eg = exp2i(acc[2][r]);                                              \
    float Eo = exp2i(acc[3][r]);                                              \
    float gf = __builtin_amdgcn_rcpf(1.f + Ef);                               \
    float ig = (1.f - Eg) * __builtin_amdgcn_rcpf((1.f + Ei) * (1.f + Eg));   \
    float cv = fmaf(gf, cc[r], ig);                                           \
    cc[r] = cv;                                                               \
    float Ec = exp2i(cv * NL2E2);                                             \
    float hv = (1.f - Ec) * __builtin_amdgcn_rcpf((1.f + Eo) * (1.f + Ec));   \
    (hw)[r * STR] = f2bf(hv);                                                 \
  }

  for (int tt = 0; tt < TLEN; tt += 2) {
    {
      const int t = tt;
      if (fon && t > 0) {
        *(uint2*)cfp = *(const uint2*)fl0;
        cfp += HID;
      }
      short8 Va[CH];
#pragma unroll
      for (int c = 0; c < CH; ++c)
        Va[c] = *(const short8*)(ard0 + c * 32 + quad * 8);
      float4v acc[4];
#pragma unroll
      for (int q = 0; q < 4; ++q)
        acc[q] = (float4v){bias[q], bias[q], bias[q], bias[q]};
#pragma unroll
      for (int q = 0; q < 4; ++q)
#pragma unroll
        for (int c = 0; c < CH; ++c)
          acc[q] = __builtin_amdgcn_mfma_f32_16x16x32_bf16(Va[c], Vb[q][c], acc[q], 0, 0, 0);
      if (st) {
        *(short8*)xd1 = xO;
        if (t + 3 < TLEN) xO = *(const short8*)fp;
      }
      fp += XSH;
      ACT_FB(hw1)
      lds_barrier();
    }
    {
      const int t = tt + 1;
      if (fon) {
        *(uint2*)cfp = *(const uint2*)fl1;
        cfp += HID;
      }
      short8 Va[CH];
#pragma unroll
      for (int c = 0; c < CH; ++c)
        Va[c] = *(const short8*)(ard1 + c * 32 + quad * 8);
      float4v acc[4];
#pragma unroll
      for (int q = 0; q < 4; ++q)
        acc[q] = (float4v){bias[q], bias[q], bias[q], bias[q]};
#pragma unroll
      for (int q = 0; q < 4; ++q)
#pragma unroll
        for (int c = 0; c < CH; ++c)
          acc[q] = __builtin_amdgcn_mfma_f32_16x16x32_bf16(Va[c], Vb[q][c], acc[q], 0, 0, 0);
      if (st) {
        if (t + 1 < TLEN) *(short8*)xd0 = xE;
        if (t + 3 < TLEN) xE = *(const short8*)fp;
      }
      fp += XSH;
      ACT_FB(hw0)
      lds_barrier();
    }
  }
  if (fon) *(uint2*)cfp = *(const uint2*)fl0;
#undef ACT_FB
}

__global__ __launch_bounds__(256, 1) void lstm_fb(
    const unsigned short* __restrict__ fHR, const unsigned short* __restrict__ fHL,
    const unsigned short* __restrict__ fAR, const unsigned short* __restrict__ fAL,
    const unsigned short* __restrict__ btA_r, const unsigned short* __restrict__ btA_l,
    const unsigned short* __restrict__ btArm_r, const unsigned short* __restrict__ btArm_l,
    const float* __restrict__ b0i, const float* __restrict__ b0h,
    const float* __restrict__ b1i, const float* __restrict__ b1h,
    const float* __restrict__ b2i, const float* __restrict__ b2h,
    const float* __restrict__ b3i, const float* __restrict__ b3h,
    unsigned short* __restrict__ combined) {
  __shared__ __align__(16) unsigned short A0[2304];
  __shared__ __align__(16) unsigned short A1[2304];
  int blk = blockIdx.x;
  int wave = threadIdx.x >> 6;
  if (blk < 16) {
    int lr = blk >> 3, tl = blk & 7;
    lstm_core_fb<64, 4, 136, 16, 6, 64, 4>(
        A0, A1, lr ? btA_l : btA_r, lr ? b2i : b0i, lr ? b2h : b0h,
        (lr ? fHL : fHR) + (size_t)tl * 512 * 768,
        combined + (lr ? 96 : 0), tl * 16, 0, wave * 16);
  } else {
    int a = blk - 16;
    int la = a >> 2, tl = a & 3;
    lstm_core_fb<32, 2, 72, 32, 1, 32, 4>(
        A0, A1, la ? btArm_l : btArm_r, la ? b3i : b1i, la ? b3h : b1h,
        (la ? fAL : fAR) + (size_t)tl * 512 * 256,
        combined + (la ? 160 : 64), tl * 32, (wave >> 1) * 16, (wave & 1) * 16);
  }
}

// ---------------- K3: attention + FC (512 threads, bf16 combined) ---------

__global__ __launch_bounds__(512) void attn_kernel(const unsigned short* __restrict__ combined,
                                                   const float* __restrict__ att_w,
                                                   const float* __restrict__ fc_w,
                                                   const float* __restrict__ fc_b,
                                                   float* __restrict__ dout) {
  __shared__ float sc[TLEN];
  __shared__ float aw[HID];
  __shared__ float pctx[8][HID];
  __shared__ float ctx[HID];
  __shared__ float red[8];
  int b = blockIdx.x, tid = threadIdx.x;
  int lane = tid & 63, wave = tid >> 6;
  const unsigned short* cb = combined + (size_t)b * TLEN * HID;
  if (tid < HID) aw[tid] = att_w[tid];
  __syncthreads();
  float a0 = aw[lane], a1 = aw[lane + 64], a2 = aw[lane + 128];

  int t0 = wave * 64;
  for (int t = t0; t < t0 + 64; t += 2) {
    const unsigned short* r0 = cb + (size_t)t * HID;
    const unsigned short* r1 = r0 + HID;
    float p0 = a0 * bf2f(r0[lane]) + a1 * bf2f(r0[lane + 64]) + a2 * bf2f(r0[lane + 128]);
    float p1 = a0 * bf2f(r1[lane]) + a1 * bf2f(r1[lane + 64]) + a2 * bf2f(r1[lane + 128]);
#pragma unroll
    for (int o = 32; o; o >>= 1) {
      p0 += __shfl_xor(p0, o, 64);
      p1 += __shfl_xor(p1, o, 64);
    }
    if (lane == 0) { sc[t] = p0; sc[t + 1] = p1; }
  }
  __syncthreads();

  float e = sc[tid];
  float lmax = e;
#pragma unroll
  for (int o = 32; o; o >>= 1) lmax = fmaxf(lmax, __shfl_xor(lmax, o, 64));
  if (lane == 0) red[wave] = lmax;
  __syncthreads();
  float m = red[0];
#pragma unroll
  for (int w = 1; w < 8; ++w) m = fmaxf(m, red[w]);
  __syncthreads();
  float ex = __expf(e - m);
  float ls = ex;
#pragma unroll
  for (int o = 32; o; o >>= 1) ls += __shfl_xor(ls, o, 64);
  if (lane == 0) red[wave] = ls;
  __syncthreads();
  float S = red[0];
#pragma unroll
  for (int w = 1; w < 8; ++w) S += red[w];
  float wgt = ex / S;
  sc[tid] = wgt;
  dout[BATCH * NC + b * TLEN + tid] = wgt;  // weights (B,T,1)
  __syncthreads();

#pragma unroll
  for (int p = 0; p < 3; ++p) {
    int h = p * 64 + lane;
    float c0 = 0.f, c1 = 0.f, c2 = 0.f, c3 = 0.f;
    for (int t = t0; t < t0 + 64; t += 4) {
      c0 += sc[t] * bf2f(cb[(size_t)t * HID + h]);
      c1 += sc[t + 1] * bf2f(cb[(size_t)(t + 1) * HID + h]);
      c2 += sc[t + 2] * bf2f(cb[(size_t)(t + 2) * HID + h]);
      c3 += sc[t + 3] * bf2f(cb[(size_t)(t + 3) * HID + h]);
    }
    pctx[wave][h] = (c0 + c1) + (c2 + c3);
  }
  __syncthreads();
  if (tid < HID) {
    float s = pctx[0][tid];
#pragma unroll
    for (int w = 1; w < 8; ++w) s += pctx[w][tid];
    ctx[tid] = s;
  }
  __syncthreads();

  if (tid < NC) {
    const float* wr = fc_w + (size_t)tid * HID;
    float s0 = fc_b[tid], s1 = 0.f, s2 = 0.f, s3 = 0.f;
#pragma unroll
    for (int h = 0; h < HID; h += 4) {
      s0 += ctx[h] * wr[h];
      s1 += ctx[h + 1] * wr[h + 1];
      s2 += ctx[h + 2] * wr[h + 2];
      s3 += ctx[h + 3] * wr[h + 3];
    }
    dout[b * NC + tid] = (s0 + s1) + (s2 + s3);  // logits (B,250)
  }
}

// ---------------- launcher ----------------

extern "C" void kernel_launch(void* const* d_in, const int* in_sizes, int n_in,
                              void* d_out, int out_size, void* d_ws, size_t ws_size,
                              hipStream_t stream) {
  const float* x = (const float*)d_in[0];
  const float* wih_rh = (const float*)d_in[1];
  const float* whh_rh = (const float*)d_in[2];
  const float* bih_rh = (const float*)d_in[3];
  const float* bhh_rh = (const float*)d_in[4];
  const float* wih_ra = (const float*)d_in[5];
  const float* whh_ra = (const float*)d_in[6];
  const float* bih_ra = (const float*)d_in[7];
  const float* bhh_ra = (const float*)d_in[8];
  const float* wih_lh = (const float*)d_in[9];
  const float* whh_lh = (const float*)d_in[10];
  const float* bih_lh = (const float*)d_in[11];
  const float* bhh_lh = (const float*)d_in[12];
  const float* wih_la = (const float*)d_in[13];
  const float* whh_la = (const float*)d_in[14];
  const float* bih_la = (const float*)d_in[15];
  const float* bhh_la = (const float*)d_in[16];
  const float* att_w = (const float*)d_in[17];
  const float* fc_w = (const float*)d_in[18];
  const float* fc_b = (const float*)d_in[19];

  const size_t SZ_COMB   = (size_t)BATCH * TLEN * HID * 2;   // 25,165,824 (bf16)
  const size_t SZ_FARM_H = (size_t)8 * TLEN * 32 * 8 * 2;    // 2,097,152 (hoist)
  const size_t SZ_FARM_F = (size_t)4 * TLEN * 32 * 8 * 2;    // 1,048,576 (fb)
  const size_t SZ_F64    = (size_t)8 * TLEN * 16 * 64 * 2;   // 8,388,608
  const size_t SZ_F48    = (size_t)8 * TLEN * 16 * 48 * 2;   // 6,291,456
  const size_t SZ_PRE    = (size_t)32 * TLEN * 1024 * 2;     // 33,554,432
  const size_t NEED_FULL = SZ_COMB + 2 * SZ_FARM_H + 2 * SZ_F64 + 2 * SZ_PRE;
  bool hoist = ws_size >= NEED_FULL;

  char* p = (char*)d_ws;
  unsigned short* combined = (unsigned short*)p; p += SZ_COMB;
  unsigned short *fAR, *fAL;
  unsigned short *fHR, *fHL, *preR = nullptr, *preL = nullptr;
  unsigned short *btA_r = nullptr, *btA_l = nullptr, *btArm_r = nullptr, *btArm_l = nullptr;
  if (hoist) {
    fAR = (unsigned short*)p; p += SZ_FARM_H;
    fAL = (unsigned short*)p; p += SZ_FARM_H;
    fHR = (unsigned short*)p; p += SZ_F64;
    fHL = (unsigned short*)p; p += SZ_F64;
    preR = (unsigned short*)p; p += SZ_PRE;
    preL = (unsigned short*)p; p += SZ_PRE;
  } else {
    fAR = (unsigned short*)p; p += SZ_FARM_F;
    fAL = (unsigned short*)p; p += SZ_FARM_F;
    fHR = (unsigned short*)p; p += SZ_F48;
    fHL = (unsigned short*)p; p += SZ_F48;
    btA_r = (unsigned short*)p; p += 65536;
    btA_l = (unsigned short*)p; p += 65536;
    btArm_r = (unsigned short*)p; p += 16384;
    btArm_l = (unsigned short*)p;
  }

  prep_kernel<<<dim3((BATCH * TLEN + 255) / 256), 256, 0, stream>>>(
      x, fHR, fHL, fAR, fAL, hoist ? 1 : 0);
  if (hoist) {
    pregemm_kernel<<<dim3(256), 256, 0, stream>>>(
        fHR, fHL, wih_rh, wih_lh, bih_rh, bhh_rh, bih_lh, bhh_lh, preR, preL);
    lstm_hoist<<<dim3(96), 256, 0, stream>>>(
        fAR, fAL, whh_rh, whh_lh, wih_ra, whh_ra, wih_la, whh_la,
        preR, preL, bih_ra, bhh_ra, bih_la, bhh_la, combined);
  } else {
    pack_kernel<<<dim3(4), 256, 0, stream>>>(
        wih_rh, whh_rh, wih_ra, whh_ra, wih_lh, whh_lh, wih_la, whh_la,
        btA_r, btA_l, btArm_r, btArm_l);
    lstm_fb<<<dim3(24), 256, 0, stream>>>(
        fHR, fHL, fAR, fAL, btA_r, btA_l, btArm_r, btArm_l,
        bih_rh, bhh_rh, bih_ra, bhh_ra, bih_lh, bhh_lh, bih_la, bhh_la, combined);
  }
  attn_kernel<<<dim3(BATCH), 512, 0, stream>>>(combined, att_w, fc_w, fc_b, (float*)d_out);
}